// Round 16
// baseline (245.387 us; speedup 1.0000x reference)
//
#include <hip/hip_runtime.h>
#include <stdint.h>

typedef unsigned short u16;
typedef unsigned int u32;
typedef short bf8_t __attribute__((ext_vector_type(8)));   // 8 bf16 = 4 VGPR
typedef float f4_t  __attribute__((ext_vector_type(4)));
typedef float f16_t __attribute__((ext_vector_type(16)));  // 32x32 MFMA C/D

#define LOG2E 1.44269504088896340736f

// packed f32x2 -> bf16x2 (RNE), single instruction
static __device__ __forceinline__ u32 pkbf(float lo, float hi){
  u32 r; asm("v_cvt_pk_bf16_f32 %0, %1, %2" : "=v"(r) : "v"(lo), "v"(hi)); return r;
}

// pair-sum across (lane, lane^32) via permlane32_swap (no LDS pipe)
static __device__ __forceinline__ float pair_add(float v, bool hi5){
  union { float f; u32 u; } a; a.f = v;
  auto r = __builtin_amdgcn_permlane32_swap(a.u, a.u, false, false);
  union { u32 u; float f; } p; p.u = hi5 ? r[0] : r[1];
  return v + p.f;
}

// Convert one 32x32 C'-tile (lane = n-col l31, regs = m per C-layout
// m=(r&3)+8*(r>>2)+4*l5) into two A/B frags with frag-k = m.
static __device__ __forceinline__ void cvt_tile(const f16_t c, bf8_t& f0, bf8_t& f1){
  u32 p0 = pkbf(c[0], c[1]),  p1 = pkbf(c[2], c[3]);
  u32 p2 = pkbf(c[4], c[5]),  p3 = pkbf(c[6], c[7]);
  u32 p4 = pkbf(c[8], c[9]),  p5 = pkbf(c[10], c[11]);
  u32 p6 = pkbf(c[12], c[13]), p7 = pkbf(c[14], c[15]);
  auto r02 = __builtin_amdgcn_permlane32_swap(p0, p2, false, false);
  auto r13 = __builtin_amdgcn_permlane32_swap(p1, p3, false, false);
  auto r46 = __builtin_amdgcn_permlane32_swap(p4, p6, false, false);
  auto r57 = __builtin_amdgcn_permlane32_swap(p5, p7, false, false);
  union { u32 u[4]; bf8_t b; } x0, x1;
  x0.u[0] = r02[0]; x0.u[1] = r13[0]; x0.u[2] = r02[1]; x0.u[3] = r13[1];
  x1.u[0] = r46[0]; x1.u[1] = r57[0]; x1.u[2] = r46[1]; x1.u[3] = r57[1];
  f0 = x0.b; f1 = x1.b;
}

#define MFMA32(a, b, c) __builtin_amdgcn_mfma_f32_32x32x16_bf16(a, b, c, 0, 0, 0)

// 16B/lane global->LDS DMA: lane l reads g(per-lane addr), lands at lds+l*16B.
static __device__ __forceinline__ void dma16(const u16* g, u16* l){
  __builtin_amdgcn_global_load_lds(
      (const __attribute__((address_space(1))) u32*)g,
      (__attribute__((address_space(3))) u32*)l,
      16, 0, 0);
}

// counted vmcnt wait (assembler sets lgkm/exp to no-wait); rule #18 fence after
#define WAITV(N) do { asm volatile("s_waitcnt vmcnt(" #N ")" ::: "memory"); \
                      __builtin_amdgcn_sched_barrier(0); } while(0)

// One DMA-ring GEMM iteration. Ring depth 4 (4KB/wave), lookahead 3.
// Issue-after-read: any compiler motion of the dma makes the wait stricter.
// Counting: at iter ks, issued chunks <= ks+2 -> vmcnt leaves newest 2
// (ks+1,ks+2) -> chunk ks complete, regardless of older unrelated loads.
#define WITER(ks, N, WA) \
  { WAITV(N); \
    bf8_t wf = *reinterpret_cast<const bf8_t*>(ring + (((ks)&3)*512) + fragoff); \
    const int ko = (ks)*16 + 8*l5; \
    bf8_t x0 = *reinterpret_cast<const bf8_t*>(&xt[l31*XS + ko]); \
    bf8_t x1 = *reinterpret_cast<const bf8_t*>(&xt[(32+l31)*XS + ko]); \
    if (WA){ c0 = MFMA32(wf, x0, c0); c1 = MFMA32(wf, x1, c1); } \
    else   { c0 = MFMA32(x0, wf, c0); c1 = MFMA32(x1, wf, c1); } \
    if ((ks)+3 < 16) dma16(wsrc + ((ks)+3)*512, ring + (((ks)+3)&3)*512); }

#define WLOOP(WA) \
  WITER(0,2,WA) WITER(1,2,WA) WITER(2,2,WA) WITER(3,2,WA) WITER(4,2,WA) \
  WITER(5,2,WA) WITER(6,2,WA) WITER(7,2,WA) WITER(8,2,WA) WITER(9,2,WA) \
  WITER(10,2,WA) WITER(11,2,WA) WITER(12,2,WA) WITER(13,2,WA) WITER(14,1,WA) WITER(15,0,WA)

#define WPRO() do { dma16(wsrc, ring); dma16(wsrc + 512, ring + 512); \
                    dma16(wsrc + 1024, ring + 1024); } while(0)

// ---------------- pre-kernels ----------------

// prep: blocks [0,128) = weight pack; blocks [128, 353) = CPB MLP (1 row each).
__global__ __launch_bounds__(256)
void prep_kernel(const float* __restrict__ qkvw, const float* __restrict__ projw,
                 const float* __restrict__ tab, const float* __restrict__ w1,
                 const float* __restrict__ b1, const float* __restrict__ w2,
                 u16* __restrict__ wpk, float* __restrict__ tbl){
  __shared__ float red[4][8];
  if (blockIdx.x < 128){
    int u = blockIdx.x * 256 + threadIdx.x;   // 0..32767, one 8-elem frag each
    int hb  = u >> 10;
    int ks  = (u >> 6) & 15;
    int l5  = (u >> 5) & 1;
    int l31 = u & 31;
    int row = hb * 32 + l31, col = ks * 16 + l5 * 8;
    const float* src = (row < 768) ? (qkvw + (size_t)row * 256 + col)
                                   : (projw + (size_t)(row - 768) * 256 + col);
    float4 v0 = *reinterpret_cast<const float4*>(src);
    float4 v1 = *reinterpret_cast<const float4*>(src + 4);
    uint4 p;
    p.x = pkbf(v0.x, v0.y); p.y = pkbf(v0.z, v0.w);
    p.z = pkbf(v1.x, v1.y); p.w = pkbf(v1.z, v1.w);
    *reinterpret_cast<uint4*>(wpk + (size_t)u * 8) = p;
  } else {
    int i = blockIdx.x - 128;                 // 0..224
    int tid = threadIdx.x;
    int wv = tid >> 6, lane = tid & 63;
    float c0 = tab[2*i], c1 = tab[2*i+1];
    int j0 = tid * 2;
    float4 w14 = *reinterpret_cast<const float4*>(w1 + 2*j0);
    float2 b12 = *reinterpret_cast<const float2*>(b1 + j0);
    float h0 = fmaxf(fmaf(c1, w14.y, fmaf(c0, w14.x, b12.x)), 0.f);
    float h1 = fmaxf(fmaf(c1, w14.w, fmaf(c0, w14.z, b12.y)), 0.f);
    float part[8];
    #pragma unroll
    for (int hh = 0; hh < 8; hh++){
      float2 w22 = *reinterpret_cast<const float2*>(w2 + hh*512 + j0);
      part[hh] = fmaf(h1, w22.y, h0 * w22.x);
    }
    #pragma unroll
    for (int hh = 0; hh < 8; hh++)
      #pragma unroll
      for (int off = 1; off < 64; off <<= 1)
        part[hh] += __shfl_xor(part[hh], off);
    if (lane == 0){
      #pragma unroll
      for (int hh = 0; hh < 8; hh++) red[wv][hh] = part[hh];
    }
    __syncthreads();
    if (tid < 8)
      tbl[i*8 + tid] = (red[0][tid] + red[1][tid]) + (red[2][tid] + red[3][tid]);
  }
}

// bias for S^T = K.Q^T C-layout (R4), PRE-SHIFTED by -(qs+24) (R14)
__global__ void cpbgather_kernel(const float* __restrict__ tbl, const int* __restrict__ idx,
                                 const float* __restrict__ scale, float* __restrict__ biasF,
                                 float* __restrict__ scf){
  int u = blockIdx.x * blockDim.x + threadIdx.x;   // 0..32767
  int rl   = u & 3;
  int lane = (u >> 2) & 63;
  int r4   = (u >> 8) & 3;
  int tile = (u >> 10) & 3;       // kt*2 + qt
  int hh   = (u >> 12) & 7;
  int qt = tile & 1, kt = tile >> 1;
  int query = 32*qt + (lane & 31);
  int key   = 32*kt + rl + 8*r4 + 4*(lane >> 5);
  int id = idx[query*64 + key];
  float xv = tbl[id*8 + hh];
  float s = 1.f / (1.f + expf(-xv));
  float qsh = expf(fminf(scale[hh], 4.6051701859880913680f)) * LOG2E;
  biasF[u] = 16.f * s * LOG2E - (qsh + 24.0f);
  if (u < 8) scf[u] = qsh;
}

// ---------------- main fused kernel (R16: DMA weight rings) ----------------
// R15 ablation: const-weights = ~63us vs 107 -> weight path latency-exposed
// (VGPR-starved pipelining at the 128-reg cap). Fix: global_load_lds DMA into
// wave-private 4KB LDS rings (zero VGPR footprint, counted vmcnt, 3 deep).
// q/k/v rings live in dead olds; proj ring in dead xlds. New barrier after
// v-pass retires rings before S's O^T writes to olds.
#define XS 264    // x / O tile stride in u16 (256+8); 528 B

__global__ __launch_bounds__(512, 4)
void winattn_kernel(const float* __restrict__ x, const u16* __restrict__ wpk,
                    const float* __restrict__ qb, const float* __restrict__ vbias,
                    const float* __restrict__ biasF, const float* __restrict__ scf,
                    const float* __restrict__ projb, float* __restrict__ out){
  __shared__ u16 xlds[64 * XS];   // x bf16; proj weight rings after x dead
  __shared__ u16 olds[64 * XS];   // q/k/v weight rings; O^T after post-v barrier

  const int b = blockIdx.x;
  const int t = threadIdx.x;
  const int w = t >> 6, lane = t & 63;
  const int l31 = lane & 31, l5 = lane >> 5;
  const bool hi5 = (l5 != 0);
  const int h = w;
  const int fragoff = l5 * 256 + l31 * 8;   // lane*16B, in u16 units

  u16* ringO = &olds[w * 2048];   // 4KB wave-private ring (q/k/v passes)
  u16* ringX = &xlds[w * 2048];   // 4KB wave-private ring (proj pass)
  const u16* wq_src = wpk + (size_t)h * 8192 + fragoff;
  const u16* wk_src = wpk + (size_t)(8 + h) * 8192 + fragoff;
  const u16* wv_src = wpk + (size_t)(16 + h) * 8192 + fragoff;
  const u16* wp_src = wpk + (size_t)(24 + w) * 8192 + fragoff;

  // ---- phase 0: stage x[b] -> LDS bf16 (nt reads); q-ring prologue hidden ----
  {
    const u16* wsrc = wq_src; u16* ring = ringO;
    WPRO();                                       // q chunks 0-2 (free under x-stage)
    const f4_t* xg = reinterpret_cast<const f4_t*>(x + (size_t)b * 16384);
    #pragma unroll
    for (int i = 0; i < 8; i++){
      int fi = t + 512 * i;
      f4_t v = __builtin_nontemporal_load(xg + fi);
      uint2 p; p.x = pkbf(v[0], v[1]); p.y = pkbf(v[2], v[3]);
      *reinterpret_cast<uint2*>(&xlds[(fi >> 6) * XS + (fi & 63) * 4]) = p;
    }
  }
  __syncthreads();

  bf8_t qf0, qf1, qf2, qf3;
  bf8_t kf0, kf1, kf2, kf3;
  bf8_t vf0, vf1, vf2, vf3;
  const float qs = scf[h];

  // ---- q-pass (ring DMA) ----
  {
    f16_t c0, c1;
    #pragma unroll
    for (int r = 0; r < 16; r++){
      float bqr = qb[32*h + (r & 3) + 8*(r >> 2) + 4*l5];
      c0[r] = bqr; c1[r] = bqr;
    }
    const u16* wsrc = wq_src; u16* ring = ringO; const u16* xt = xlds;
    __builtin_amdgcn_s_setprio(1);
    WLOOP(1)                                      // W as A-operand
    __builtin_amdgcn_s_setprio(0);
    { const u16* wsrc = wk_src; u16* ring = ringO; WPRO(); }  // k prologue (slots 0-2 free: q read them at iters 12,13,14... chunks 12,13,14; all consumed)
    {
      float sq = 0.f;
      #pragma unroll
      for (int r = 0; r < 16; r++) sq = fmaf(c0[r], c0[r], sq);
      sq = pair_add(sq, hi5);
      float iq = qs * __builtin_amdgcn_rsqf(fmaxf(sq, 1e-24f));
      #pragma unroll
      for (int r = 0; r < 16; r++) c0[r] *= iq;
      cvt_tile(c0, qf0, qf1);
    }
    {
      float sq = 0.f;
      #pragma unroll
      for (int r = 0; r < 16; r++) sq = fmaf(c1[r], c1[r], sq);
      sq = pair_add(sq, hi5);
      float iq = qs * __builtin_amdgcn_rsqf(fmaxf(sq, 1e-24f));
      #pragma unroll
      for (int r = 0; r < 16; r++) c1[r] *= iq;
      cvt_tile(c1, qf2, qf3);
    }
  }

  // ---- k-pass (ring DMA; prologue already issued) ----
  {
    f16_t c0, c1;
    #pragma unroll
    for (int r = 0; r < 16; r++){ c0[r] = 0.f; c1[r] = 0.f; }
    const u16* wsrc = wk_src; u16* ring = ringO; const u16* xt = xlds;
    __builtin_amdgcn_s_setprio(1);
    WLOOP(1)
    __builtin_amdgcn_s_setprio(0);
    { const u16* wsrc = wv_src; u16* ring = ringO; WPRO(); }  // v prologue
    {
      float sk = 0.f;
      #pragma unroll
      for (int r = 0; r < 16; r++) sk = fmaf(c0[r], c0[r], sk);
      sk = pair_add(sk, hi5);
      float ik = __builtin_amdgcn_rsqf(fmaxf(sk, 1e-24f));
      #pragma unroll
      for (int r = 0; r < 16; r++) c0[r] *= ik;
      cvt_tile(c0, kf0, kf1);
    }
    {
      float sk = 0.f;
      #pragma unroll
      for (int r = 0; r < 16; r++) sk = fmaf(c1[r], c1[r], sk);
      sk = pair_add(sk, hi5);
      float ik = __builtin_amdgcn_rsqf(fmaxf(sk, 1e-24f));
      #pragma unroll
      for (int r = 0; r < 16; r++) c1[r] *= ik;
      cvt_tile(c1, kf2, kf3);
    }
  }

  // ---- v-pass (ring DMA; prologue already issued) ----
  {
    f16_t c0, c1;
    float bv = vbias[32*h + l31];
    #pragma unroll
    for (int r = 0; r < 16; r++){ c0[r] = bv; c1[r] = bv; }
    const u16* wsrc = wv_src; u16* ring = ringO; const u16* xt = xlds;
    __builtin_amdgcn_s_setprio(1);
    WLOOP(0)                                      // W as B-operand
    __builtin_amdgcn_s_setprio(0);
    cvt_tile(c0, vf0, vf1);
    cvt_tile(c1, vf2, vf3);
  }
  __syncthreads();   // rings in olds retired; xlds dead -> olds becomes O, xlds hosts proj ring

  // ---- phase S (proj ring prologue hidden under it) ----
  { const u16* wsrc = wp_src; u16* ring = ringX; WPRO(); }
  #pragma unroll
  for (int nt = 0; nt < 2; nt++){
    union { f16_t c; f4_t q[4]; } S0, S1;
    {
      const f4_t* bf0 = reinterpret_cast<const f4_t*>(biasF) + (h*4 + nt    ) * 256 + lane;
      const f4_t* bf1 = reinterpret_cast<const f4_t*>(biasF) + (h*4 + 2 + nt) * 256 + lane;
      #pragma unroll
      for (int r4 = 0; r4 < 4; r4++){ S0.q[r4] = bf0[r4 * 64]; S1.q[r4] = bf1[r4 * 64]; }
    }
    f16_t s0 = S0.c, s1 = S1.c;
    bf8_t qfa = nt ? qf2 : qf0, qfb = nt ? qf3 : qf1;
    __builtin_amdgcn_s_setprio(1);
    s0 = MFMA32(kf0, qfa, s0); s0 = MFMA32(kf1, qfb, s0);
    s1 = MFMA32(kf2, qfa, s1); s1 = MFMA32(kf3, qfb, s1);
    __builtin_amdgcn_s_setprio(0);
    #pragma unroll
    for (int r = 0; r < 16; r++){
      s0[r] = __builtin_amdgcn_exp2f(s0[r]);
      s1[r] = __builtin_amdgcn_exp2f(s1[r]);
    }
    float a0 = 0.f, a1 = 0.f, a2 = 0.f, a3 = 0.f;
    #pragma unroll
    for (int r4 = 0; r4 < 4; r4++){
      a0 += s0[4*r4 + 0] + s1[4*r4 + 0];
      a1 += s0[4*r4 + 1] + s1[4*r4 + 1];
      a2 += s0[4*r4 + 2] + s1[4*r4 + 2];
      a3 += s0[4*r4 + 3] + s1[4*r4 + 3];
    }
    float ssum = pair_add((a0 + a1) + (a2 + a3), hi5);
    float invr = __builtin_amdgcn_rcpf(ssum);
    bf8_t pf0, pf1, pf2, pf3;
    cvt_tile(s0, pf0, pf1);
    cvt_tile(s1, pf2, pf3);
    f16_t co;
    #pragma unroll
    for (int r = 0; r < 16; r++) co[r] = 0.f;
    __builtin_amdgcn_s_setprio(1);
    co = MFMA32(vf0, pf0, co); co = MFMA32(vf1, pf1, co);
    co = MFMA32(vf2, pf2, co); co = MFMA32(vf3, pf3, co);
    __builtin_amdgcn_s_setprio(0);
    #pragma unroll
    for (int r4 = 0; r4 < 4; r4++){
      uint2 p;
      p.x = pkbf(co[4*r4 + 0] * invr, co[4*r4 + 1] * invr);
      p.y = pkbf(co[4*r4 + 2] * invr, co[4*r4 + 3] * invr);
      *reinterpret_cast<uint2*>(&olds[(32*nt + l31) * XS + 32*h + 8*r4 + 4*l5]) = p;
    }
  }
  __syncthreads();   // O complete; proj ring chunks 0-2 landed (drained here)

  // ---- proj (ring DMA, A from olds; nt stores) ----
  {
    f16_t c0, c1;
    float pbv = projb[32*w + l31];
    #pragma unroll
    for (int r = 0; r < 16; r++){ c0[r] = pbv; c1[r] = pbv; }
    const u16* wsrc = wp_src; u16* ring = ringX; const u16* xt = olds;
    __builtin_amdgcn_s_setprio(1);
    WLOOP(0)
    __builtin_amdgcn_s_setprio(0);
    float* og = out + (size_t)b * 16384;
    #pragma unroll
    for (int r = 0; r < 16; r++){
      int m = (r & 3) + 8*(r >> 2) + 4*l5;
      __builtin_nontemporal_store(c0[r], &og[m * 256 + 32*w + l31]);
      __builtin_nontemporal_store(c1[r], &og[(32 + m) * 256 + 32*w + l31]);
    }
  }
}

// ---------------- launch ----------------
extern "C" void kernel_launch(void* const* d_in, const int* in_sizes, int n_in,
                              void* d_out, int out_size, void* d_ws, size_t ws_size,
                              hipStream_t stream){
  const float* x     = (const float*)d_in[0];
  const float* qkvw  = (const float*)d_in[1];
  const float* qb    = (const float*)d_in[2];
  const float* vb    = (const float*)d_in[3];
  const float* scale = (const float*)d_in[4];
  const float* w1    = (const float*)d_in[5];
  const float* b1    = (const float*)d_in[6];
  const float* w2    = (const float*)d_in[7];
  const float* pw    = (const float*)d_in[8];
  const float* pb    = (const float*)d_in[9];
  const float* tab   = (const float*)d_in[10];
  const int*   idx   = (const int*)d_in[11];
  float* out = (float*)d_out;

  char* ws = (char*)d_ws;
  u16*   wpkp = (u16*)ws;                    // 524288 B : packed weights (frag order)
  float* bias = (float*)(ws + 524288);       // 131072 B : CPB bias, pre-shifted
  float* tbl  = (float*)(ws + 655360);       //   7200 B : cpb MLP out [225][8]
  float* scfp = (float*)(ws + 662560);       //     32 B : folded per-head scale

  hipLaunchKernelGGL(prep_kernel,     dim3(353), dim3(256), 0, stream,
                     qkvw, pw, tab, w1, b1, w2, wpkp, tbl);
  hipLaunchKernelGGL(cpbgather_kernel,dim3(128), dim3(256), 0, stream, tbl, idx, scale, bias, scfp);
  hipLaunchKernelGGL(winattn_kernel,  dim3(2048), dim3(512), 0, stream,
                     x, wpkp, qb, vb, bias, scfp, pb, out);
}

// Round 17
// 115.309 us; speedup vs baseline: 2.1281x; 2.1281x over previous
//
#include <hip/hip_runtime.h>
#include <stdint.h>

typedef unsigned short u16;
typedef unsigned int u32;
typedef short bf8_t __attribute__((ext_vector_type(8)));   // 8 bf16 = 4 VGPR
typedef float f4_t  __attribute__((ext_vector_type(4)));
typedef float f16_t __attribute__((ext_vector_type(16)));  // 32x32 MFMA C/D

#define LOG2E 1.44269504088896340736f

// packed f32x2 -> bf16x2 (RNE), single instruction
static __device__ __forceinline__ u32 pkbf(float lo, float hi){
  u32 r; asm("v_cvt_pk_bf16_f32 %0, %1, %2" : "=v"(r) : "v"(lo), "v"(hi)); return r;
}

// pair-sum across (lane, lane^32) via permlane32_swap (no LDS pipe)
static __device__ __forceinline__ float pair_add(float v, bool hi5){
  union { float f; u32 u; } a; a.f = v;
  auto r = __builtin_amdgcn_permlane32_swap(a.u, a.u, false, false);
  union { u32 u; float f; } p; p.u = hi5 ? r[0] : r[1];
  return v + p.f;
}

// Convert one 32x32 C'-tile (lane = n-col l31, regs = m per C-layout
// m=(r&3)+8*(r>>2)+4*l5) into two A/B frags with frag-k = m.
// permlane32_swap(a,b) -> {[a_lo|b_lo], [a_hi|b_hi]} = frag words u[0]/u[2].
static __device__ __forceinline__ void cvt_tile(const f16_t c, bf8_t& f0, bf8_t& f1){
  u32 p0 = pkbf(c[0], c[1]),  p1 = pkbf(c[2], c[3]);
  u32 p2 = pkbf(c[4], c[5]),  p3 = pkbf(c[6], c[7]);
  u32 p4 = pkbf(c[8], c[9]),  p5 = pkbf(c[10], c[11]);
  u32 p6 = pkbf(c[12], c[13]), p7 = pkbf(c[14], c[15]);
  auto r02 = __builtin_amdgcn_permlane32_swap(p0, p2, false, false);
  auto r13 = __builtin_amdgcn_permlane32_swap(p1, p3, false, false);
  auto r46 = __builtin_amdgcn_permlane32_swap(p4, p6, false, false);
  auto r57 = __builtin_amdgcn_permlane32_swap(p5, p7, false, false);
  union { u32 u[4]; bf8_t b; } x0, x1;
  x0.u[0] = r02[0]; x0.u[1] = r13[0]; x0.u[2] = r02[1]; x0.u[3] = r13[1];
  x1.u[0] = r46[0]; x1.u[1] = r57[0]; x1.u[2] = r46[1]; x1.u[3] = r57[1];
  f0 = x0.b; f1 = x1.b;
}

#define MFMA32(a, b, c) __builtin_amdgcn_mfma_f32_32x32x16_bf16(a, b, c, 0, 0, 0)

// ---------------- pre-kernels ----------------

// prep: blocks [0,128) = weight pack; blocks [128, 353) = CPB MLP (1 row each).
__global__ __launch_bounds__(256)
void prep_kernel(const float* __restrict__ qkvw, const float* __restrict__ projw,
                 const float* __restrict__ tab, const float* __restrict__ w1,
                 const float* __restrict__ b1, const float* __restrict__ w2,
                 u16* __restrict__ wpk, float* __restrict__ tbl){
  __shared__ float red[4][8];
  if (blockIdx.x < 128){
    int u = blockIdx.x * 256 + threadIdx.x;   // 0..32767, one 8-elem frag each
    int hb  = u >> 10;
    int ks  = (u >> 6) & 15;
    int l5  = (u >> 5) & 1;
    int l31 = u & 31;
    int row = hb * 32 + l31, col = ks * 16 + l5 * 8;
    const float* src = (row < 768) ? (qkvw + (size_t)row * 256 + col)
                                   : (projw + (size_t)(row - 768) * 256 + col);
    float4 v0 = *reinterpret_cast<const float4*>(src);
    float4 v1 = *reinterpret_cast<const float4*>(src + 4);
    uint4 p;
    p.x = pkbf(v0.x, v0.y); p.y = pkbf(v0.z, v0.w);
    p.z = pkbf(v1.x, v1.y); p.w = pkbf(v1.z, v1.w);
    *reinterpret_cast<uint4*>(wpk + (size_t)u * 8) = p;
  } else {
    int i = blockIdx.x - 128;                 // 0..224
    int tid = threadIdx.x;
    int wv = tid >> 6, lane = tid & 63;
    float c0 = tab[2*i], c1 = tab[2*i+1];
    int j0 = tid * 2;
    float4 w14 = *reinterpret_cast<const float4*>(w1 + 2*j0);
    float2 b12 = *reinterpret_cast<const float2*>(b1 + j0);
    float h0 = fmaxf(fmaf(c1, w14.y, fmaf(c0, w14.x, b12.x)), 0.f);
    float h1 = fmaxf(fmaf(c1, w14.w, fmaf(c0, w14.z, b12.y)), 0.f);
    float part[8];
    #pragma unroll
    for (int hh = 0; hh < 8; hh++){
      float2 w22 = *reinterpret_cast<const float2*>(w2 + hh*512 + j0);
      part[hh] = fmaf(h1, w22.y, h0 * w22.x);
    }
    #pragma unroll
    for (int hh = 0; hh < 8; hh++)
      #pragma unroll
      for (int off = 1; off < 64; off <<= 1)
        part[hh] += __shfl_xor(part[hh], off);
    if (lane == 0){
      #pragma unroll
      for (int hh = 0; hh < 8; hh++) red[wv][hh] = part[hh];
    }
    __syncthreads();
    if (tid < 8)
      tbl[i*8 + tid] = (red[0][tid] + red[1][tid]) + (red[2][tid] + red[3][tid]);
  }
}

// bias for S^T = K.Q^T C-layout (R4), PRE-SHIFTED by -(qs+24) (R14)
__global__ void cpbgather_kernel(const float* __restrict__ tbl, const int* __restrict__ idx,
                                 const float* __restrict__ scale, float* __restrict__ biasF,
                                 float* __restrict__ scf){
  int u = blockIdx.x * blockDim.x + threadIdx.x;   // 0..32767
  int rl   = u & 3;
  int lane = (u >> 2) & 63;
  int r4   = (u >> 8) & 3;
  int tile = (u >> 10) & 3;       // kt*2 + qt
  int hh   = (u >> 12) & 7;
  int qt = tile & 1, kt = tile >> 1;
  int query = 32*qt + (lane & 31);
  int key   = 32*kt + rl + 8*r4 + 4*(lane >> 5);
  int id = idx[query*64 + key];
  float xv = tbl[id*8 + hh];
  float s = 1.f / (1.f + expf(-xv));
  float qsh = expf(fminf(scale[hh], 4.6051701859880913680f)) * LOG2E;
  biasF[u] = 16.f * s * LOG2E - (qsh + 24.0f);
  if (u < 8) scf[u] = qsh;
}

// ---------------- main fused kernel (best-known-good: R14 + unroll 8) ----------------
// 1 block/window, 8 waves, wave w = head w, 32x32x16 MFMAs.
// Ladder: 327 (R1) -> 230 (occupancy) -> 191 (in-reg cvt_tile, 32x32) ->
// 135 (frag-packed weights; 512B-stride loads were the stall) ->
// 107 (non-temporal x/out streams protect L2 residency of weights+bias).
// Closed-off dead ends (do NOT retry blindly):
//  - reg-staged prefetch: spills; phase liveness AT the 128-reg cap (R5/R7).
//  - global_load_lds wave-private rings: ~740MB phantom HBM traffic, 2.3x dur
//    (R16) - lowering/accounting hazard, needs disasm before any retry.
//  - weight-traffic halving (R13), reg-class pass-split, setprio, bias-fold
//    (R14): all neutral - the residual ~45us is weight-load LATENCY exposure
//    (R15 const-weight ablation: 63us), unfixable without reg/LDS headroom.
#define XS 264    // x / O tile stride in u16 (256+8); 528 B

__global__ __launch_bounds__(512, 4)
void winattn_kernel(const float* __restrict__ x, const u16* __restrict__ wpk,
                    const float* __restrict__ qb, const float* __restrict__ vbias,
                    const float* __restrict__ biasF, const float* __restrict__ scf,
                    const float* __restrict__ projb, float* __restrict__ out){
  __shared__ u16 xlds[64 * XS];   // x bf16
  __shared__ u16 olds[64 * XS];   // attention output bf16

  const int b = blockIdx.x;
  const int t = threadIdx.x;
  const int w = t >> 6, lane = t & 63;
  const int l31 = lane & 31, l5 = lane >> 5;
  const bool hi5 = (l5 != 0);
  const int h = w;
  const int fragoff = l5 * 256 + l31 * 8;   // within one [ks] block of 512 u16

  // ---- phase 0: stage x[b] -> LDS bf16 (non-temporal reads) ----
  {
    const f4_t* xg = reinterpret_cast<const f4_t*>(x + (size_t)b * 16384);
    #pragma unroll
    for (int i = 0; i < 8; i++){
      int fi = t + 512 * i;
      f4_t v = __builtin_nontemporal_load(xg + fi);
      uint2 p; p.x = pkbf(v[0], v[1]); p.y = pkbf(v[2], v[3]);
      *reinterpret_cast<uint2*>(&xlds[(fi >> 6) * XS + (fi & 63) * 4]) = p;
    }
  }
  __syncthreads();

  bf8_t qf0, qf1, qf2, qf3;
  bf8_t kf0, kf1, kf2, kf3;
  bf8_t vf0, vf1, vf2, vf3;
  const float qs = scf[h];

  // ---- q-pass ----
  {
    f16_t cq0, cq1;
    #pragma unroll
    for (int r = 0; r < 16; r++){
      float bqr = qb[32*h + (r & 3) + 8*(r >> 2) + 4*l5];
      cq0[r] = bqr; cq1[r] = bqr;
    }
    const u16* wqf = wpk + (size_t)h * 8192 + fragoff;
    __builtin_amdgcn_s_setprio(1);
    #pragma unroll 8
    for (int ks = 0; ks < 16; ks++){
      const int ko = ks * 16 + 8 * l5;
      bf8_t aq  = *reinterpret_cast<const bf8_t*>(wqf + ks * 512);
      bf8_t bx0 = *reinterpret_cast<const bf8_t*>(&xlds[l31 * XS + ko]);
      bf8_t bx1 = *reinterpret_cast<const bf8_t*>(&xlds[(32 + l31) * XS + ko]);
      cq0 = MFMA32(aq, bx0, cq0);
      cq1 = MFMA32(aq, bx1, cq1);
    }
    __builtin_amdgcn_s_setprio(0);
    {
      float sq = 0.f;
      #pragma unroll
      for (int r = 0; r < 16; r++) sq = fmaf(cq0[r], cq0[r], sq);
      sq = pair_add(sq, hi5);
      float iq = qs * __builtin_amdgcn_rsqf(fmaxf(sq, 1e-24f));
      #pragma unroll
      for (int r = 0; r < 16; r++) cq0[r] *= iq;
      cvt_tile(cq0, qf0, qf1);
    }
    {
      float sq = 0.f;
      #pragma unroll
      for (int r = 0; r < 16; r++) sq = fmaf(cq1[r], cq1[r], sq);
      sq = pair_add(sq, hi5);
      float iq = qs * __builtin_amdgcn_rsqf(fmaxf(sq, 1e-24f));
      #pragma unroll
      for (int r = 0; r < 16; r++) cq1[r] *= iq;
      cvt_tile(cq1, qf2, qf3);
    }
  }

  // ---- k-pass ----
  {
    f16_t ck0, ck1;
    #pragma unroll
    for (int r = 0; r < 16; r++){ ck0[r] = 0.f; ck1[r] = 0.f; }
    const u16* wkf = wpk + (size_t)(8 + h) * 8192 + fragoff;
    __builtin_amdgcn_s_setprio(1);
    #pragma unroll 8
    for (int ks = 0; ks < 16; ks++){
      const int ko = ks * 16 + 8 * l5;
      bf8_t ak  = *reinterpret_cast<const bf8_t*>(wkf + ks * 512);
      bf8_t bx0 = *reinterpret_cast<const bf8_t*>(&xlds[l31 * XS + ko]);
      bf8_t bx1 = *reinterpret_cast<const bf8_t*>(&xlds[(32 + l31) * XS + ko]);
      ck0 = MFMA32(ak, bx0, ck0);
      ck1 = MFMA32(ak, bx1, ck1);
    }
    __builtin_amdgcn_s_setprio(0);
    {
      float sk = 0.f;
      #pragma unroll
      for (int r = 0; r < 16; r++) sk = fmaf(ck0[r], ck0[r], sk);
      sk = pair_add(sk, hi5);
      float ik = __builtin_amdgcn_rsqf(fmaxf(sk, 1e-24f));
      #pragma unroll
      for (int r = 0; r < 16; r++) ck0[r] *= ik;
      cvt_tile(ck0, kf0, kf1);
    }
    {
      float sk = 0.f;
      #pragma unroll
      for (int r = 0; r < 16; r++) sk = fmaf(ck1[r], ck1[r], sk);
      sk = pair_add(sk, hi5);
      float ik = __builtin_amdgcn_rsqf(fmaxf(sk, 1e-24f));
      #pragma unroll
      for (int r = 0; r < 16; r++) ck1[r] *= ik;
      cvt_tile(ck1, kf2, kf3);
    }
  }

  // ---- v-pass ----
  {
    f16_t cv0, cv1;
    float bv = vbias[32*h + l31];
    #pragma unroll
    for (int r = 0; r < 16; r++){ cv0[r] = bv; cv1[r] = bv; }
    const u16* wvf = wpk + (size_t)(16 + h) * 8192 + fragoff;
    __builtin_amdgcn_s_setprio(1);
    #pragma unroll 8
    for (int ks = 0; ks < 16; ks++){
      const int ko = ks * 16 + 8 * l5;
      bf8_t bw  = *reinterpret_cast<const bf8_t*>(wvf + ks * 512);
      bf8_t ax0 = *reinterpret_cast<const bf8_t*>(&xlds[l31 * XS + ko]);
      bf8_t ax1 = *reinterpret_cast<const bf8_t*>(&xlds[(32 + l31) * XS + ko]);
      cv0 = MFMA32(ax0, bw, cv0);
      cv1 = MFMA32(ax1, bw, cv1);
    }
    __builtin_amdgcn_s_setprio(0);
    cvt_tile(cv0, vf0, vf1);
    cvt_tile(cv1, vf2, vf3);
  }

  // ---- phase S: S^T = K.Q^T (pre-shifted bias C-init), exp2, O^T = V.P ----
  #pragma unroll
  for (int nt = 0; nt < 2; nt++){
    union { f16_t c; f4_t q[4]; } S0, S1;
    {
      const f4_t* bf0 = reinterpret_cast<const f4_t*>(biasF) + (h*4 + nt    ) * 256 + lane;
      const f4_t* bf1 = reinterpret_cast<const f4_t*>(biasF) + (h*4 + 2 + nt) * 256 + lane;
      #pragma unroll
      for (int r4 = 0; r4 < 4; r4++){ S0.q[r4] = bf0[r4 * 64]; S1.q[r4] = bf1[r4 * 64]; }
    }
    f16_t s0 = S0.c, s1 = S1.c;
    bf8_t qfa = nt ? qf2 : qf0, qfb = nt ? qf3 : qf1;
    __builtin_amdgcn_s_setprio(1);
    s0 = MFMA32(kf0, qfa, s0); s0 = MFMA32(kf1, qfb, s0);
    s1 = MFMA32(kf2, qfa, s1); s1 = MFMA32(kf3, qfb, s1);
    __builtin_amdgcn_s_setprio(0);
    #pragma unroll
    for (int r = 0; r < 16; r++){
      s0[r] = __builtin_amdgcn_exp2f(s0[r]);
      s1[r] = __builtin_amdgcn_exp2f(s1[r]);
    }
    float a0 = 0.f, a1 = 0.f, a2 = 0.f, a3 = 0.f;
    #pragma unroll
    for (int r4 = 0; r4 < 4; r4++){
      a0 += s0[4*r4 + 0] + s1[4*r4 + 0];
      a1 += s0[4*r4 + 1] + s1[4*r4 + 1];
      a2 += s0[4*r4 + 2] + s1[4*r4 + 2];
      a3 += s0[4*r4 + 3] + s1[4*r4 + 3];
    }
    float ssum = pair_add((a0 + a1) + (a2 + a3), hi5);
    float invr = __builtin_amdgcn_rcpf(ssum);
    bf8_t pf0, pf1, pf2, pf3;
    cvt_tile(s0, pf0, pf1);
    cvt_tile(s1, pf2, pf3);
    f16_t co;
    #pragma unroll
    for (int r = 0; r < 16; r++) co[r] = 0.f;
    __builtin_amdgcn_s_setprio(1);
    co = MFMA32(vf0, pf0, co); co = MFMA32(vf1, pf1, co);
    co = MFMA32(vf2, pf2, co); co = MFMA32(vf3, pf3, co);
    __builtin_amdgcn_s_setprio(0);
    #pragma unroll
    for (int r4 = 0; r4 < 4; r4++){
      uint2 p;
      p.x = pkbf(co[4*r4 + 0] * invr, co[4*r4 + 1] * invr);
      p.y = pkbf(co[4*r4 + 2] * invr, co[4*r4 + 3] * invr);
      *reinterpret_cast<uint2*>(&olds[(32*nt + l31) * XS + 32*h + 8*r4 + 4*l5]) = p;
    }
  }
  __syncthreads();

  // ---- proj: out cols [32w,32w+32) (non-temporal stores) ----
  {
    f16_t cp0, cp1;
    float pbv = projb[32*w + l31];
    #pragma unroll
    for (int r = 0; r < 16; r++){ cp0[r] = pbv; cp1[r] = pbv; }
    const u16* wpf = wpk + (size_t)(24 + w) * 8192 + fragoff;
    __builtin_amdgcn_s_setprio(1);
    #pragma unroll 8
    for (int ks = 0; ks < 16; ks++){
      const int ko = ks * 16 + 8 * l5;
      bf8_t bw = *reinterpret_cast<const bf8_t*>(wpf + ks * 512);
      bf8_t a0 = *reinterpret_cast<const bf8_t*>(&olds[l31 * XS + ko]);
      bf8_t a1 = *reinterpret_cast<const bf8_t*>(&olds[(32 + l31) * XS + ko]);
      cp0 = MFMA32(a0, bw, cp0);
      cp1 = MFMA32(a1, bw, cp1);
    }
    __builtin_amdgcn_s_setprio(0);
    float* og = out + (size_t)b * 16384;
    #pragma unroll
    for (int r = 0; r < 16; r++){
      int m = (r & 3) + 8*(r >> 2) + 4*l5;
      __builtin_nontemporal_store(cp0[r], &og[m * 256 + 32*w + l31]);
      __builtin_nontemporal_store(cp1[r], &og[(32 + m) * 256 + 32*w + l31]);
    }
  }
}

// ---------------- launch ----------------
extern "C" void kernel_launch(void* const* d_in, const int* in_sizes, int n_in,
                              void* d_out, int out_size, void* d_ws, size_t ws_size,
                              hipStream_t stream){
  const float* x     = (const float*)d_in[0];
  const float* qkvw  = (const float*)d_in[1];
  const float* qb    = (const float*)d_in[2];
  const float* vb    = (const float*)d_in[3];
  const float* scale = (const float*)d_in[4];
  const float* w1    = (const float*)d_in[5];
  const float* b1    = (const float*)d_in[6];
  const float* w2    = (const float*)d_in[7];
  const float* pw    = (const float*)d_in[8];
  const float* pb    = (const float*)d_in[9];
  const float* tab   = (const float*)d_in[10];
  const int*   idx   = (const int*)d_in[11];
  float* out = (float*)d_out;

  char* ws = (char*)d_ws;
  u16*   wpkp = (u16*)ws;                    // 524288 B : packed weights (frag order)
  float* bias = (float*)(ws + 524288);       // 131072 B : CPB bias, pre-shifted
  float* tbl  = (float*)(ws + 655360);       //   7200 B : cpb MLP out [225][8]
  float* scfp = (float*)(ws + 662560);       //     32 B : folded per-head scale

  hipLaunchKernelGGL(prep_kernel,     dim3(353), dim3(256), 0, stream,
                     qkvw, pw, tab, w1, b1, w2, wpkp, tbl);
  hipLaunchKernelGGL(cpbgather_kernel,dim3(128), dim3(256), 0, stream, tbl, idx, scale, bias, scfp);
  hipLaunchKernelGGL(winattn_kernel,  dim3(2048), dim3(512), 0, stream,
                     x, wpkp, qb, vb, bias, scfp, pb, out);
}